// Round 8
// baseline (529.061 us; speedup 1.0000x reference)
//
#include <hip/hip_runtime.h>

#define N_ELEM 262144   // 1*512*512 per batch image
#define SPLIT 32        // slice-blocks per (batch,tensor) pair
#define NTS 256         // block size
#define SLICE_CAP 256   // per-slice candidate cap (expected ~51)
#define LSEL 2048       // select: LDS candidate cache entries (expected ~1630)
#define TIE_CAP 512
#define THRESH 2.5f     // fixed pre-filter; select falls back if counts invalid

// Order-preserving float->uint key: larger float => larger key.
__device__ __forceinline__ unsigned keyOf(float f) {
    unsigned u = __float_as_uint(f);
    return (u & 0x80000000u) ? ~u : (u | 0x80000000u);
}

__device__ __forceinline__ const float* pairSrc(int p, const float* rv, const float* ri, const float* rf) {
    int t = p % 3, b = p / 3;
    return (t == 0 ? rv : (t == 1 ? ri : rf)) + (size_t)b * N_ELEM;
}

// ---- tiny init: zero the progress counters (can't trust ws poison value) ----
__global__ void init_kernel(int* __restrict__ pairCnt, int P,
                            int* __restrict__ batchCnt, int B,
                            int* __restrict__ gcnt) {
    int i = threadIdx.x;
    for (int j = i; j < P; j += 256) pairCnt[j] = 0;
    for (int j = i; j < B; j += 256) batchCnt[j] = 0;
    if (i == 0) *gcnt = 0;
}

// ---- one fused kernel: collect slice -> (last of pair) select -> (last of
//      batch) coverage -> (last of grid) final reduce. Done-counter chained;
//      no spinning, so no deadlock regardless of scheduling. ----
__global__ __launch_bounds__(NTS) void fused_kernel(const float* __restrict__ rv,
                                                    const float* __restrict__ ri,
                                                    const float* __restrict__ rf,
                                                    int* __restrict__ cntS,
                                                    unsigned long long* __restrict__ cand,
                                                    int* __restrict__ idx_out,
                                                    int* __restrict__ pairCnt,
                                                    int* __restrict__ batchCnt,
                                                    int* __restrict__ gcnt,
                                                    float* __restrict__ lossArr,
                                                    float* __restrict__ out,
                                                    int B) {
    const int p = blockIdx.x / SPLIT;
    const int s = blockIdx.x % SPLIT;
    const int t = p % 3;
    const int bb = p / 3;
    const int K = (t == 2) ? 360 : 180;
    const int tid = threadIdx.x;

    // 48 KB LDS union, temporally disjoint phases:
    //   collect:  buf u64[256]                      (2 KB)
    //   select:   lcKey[2048] | lcIdx[2048]         (16 KB)
    //   coverage: rfbm[8192] (32K) | srcbm[4096] (16K)
    __shared__ __align__(16) unsigned char smem[49152];
    __shared__ unsigned hist[256];
    __shared__ int ties[TIE_CAP];
    __shared__ int soff[SPLIT]; __shared__ int scnt[SPLIT];
    __shared__ int s_m, s_total, s_bad;
    __shared__ unsigned s_p2; __shared__ int s_b2; __shared__ int s_cg2;
    __shared__ int s_on, s_tn, s_pickd; __shared__ unsigned s_pickb;
    __shared__ int s_last1, s_last2, s_last3;
    __shared__ int s_u, s_c;

    // ================= Phase 1: collect this slice =================
    unsigned long long* buf = (unsigned long long*)smem;
    if (tid == 0) s_m = 0;
    __syncthreads();
    const float4* p4s = (const float4*)pairSrc(p, rv, ri, rf) + (size_t)s * (N_ELEM / 4 / SPLIT);
    const int base_idx = s * (N_ELEM / SPLIT);
    for (int i = tid; i < N_ELEM / 4 / SPLIT; i += NTS) {   // 8 iterations
        float4 v = p4s[i];
        int pos;
        if (v.x > THRESH) { pos = atomicAdd(&s_m, 1); if (pos < SLICE_CAP) buf[pos] = ((unsigned long long)keyOf(v.x) << 32) | (unsigned)(base_idx + 4 * i + 0); }
        if (v.y > THRESH) { pos = atomicAdd(&s_m, 1); if (pos < SLICE_CAP) buf[pos] = ((unsigned long long)keyOf(v.y) << 32) | (unsigned)(base_idx + 4 * i + 1); }
        if (v.z > THRESH) { pos = atomicAdd(&s_m, 1); if (pos < SLICE_CAP) buf[pos] = ((unsigned long long)keyOf(v.z) << 32) | (unsigned)(base_idx + 4 * i + 2); }
        if (v.w > THRESH) { pos = atomicAdd(&s_m, 1); if (pos < SLICE_CAP) buf[pos] = ((unsigned long long)keyOf(v.w) << 32) | (unsigned)(base_idx + 4 * i + 3); }
    }
    __syncthreads();
    {
        int m = s_m;
        const bool over = (m > SLICE_CAP);
        if (over) m = SLICE_CAP;
        if (tid == 0) cntS[p * SPLIT + s] = over ? -1 : m;
        unsigned long long* myc = cand + (size_t)(p * SPLIT + s) * SLICE_CAP;
        for (int i = tid; i < m; i += NTS) myc[i] = buf[i];
    }
    __threadfence();          // each thread releases its own global stores
    __syncthreads();          // all fences done before tid0's atomic
    if (tid == 0) s_last1 = (atomicAdd(&pairCnt[p], 1) == SPLIT - 1) ? 1 : 0;
    __syncthreads();
    if (!s_last1) return;     // block-uniform exit

    // ================= Phase 2: select for pair p =================
    unsigned* lcKey = (unsigned*)smem;            // aliases buf (dead)
    unsigned* lcIdx = (unsigned*)(smem + 8192);
    int* obuf = idx_out + (size_t)p * 360;

    if (tid < 64) {           // slice counts -> offsets (wave 0 shfl scan)
        int c = (tid < SPLIT) ? cntS[p * SPLIT + tid] : 0;
        int bad = (c < 0) ? 1 : 0;
        int cc = bad ? 0 : c;
        int v = cc;
        #pragma unroll
        for (int off = 1; off < 64; off <<= 1) {
            int u = __shfl_up(v, off, 64);
            if (tid >= off) v += u;
        }
        if (tid < SPLIT) { soff[tid] = v - cc; scnt[tid] = cc; }
        if (tid == 63) s_total = v;
        unsigned long long bm = __ballot(bad != 0);
        if (tid == 0) s_bad = (bm != 0ull) ? 1 : 0;
    }
    __syncthreads();
    const int total = s_total;
    const bool fits = (!s_bad) && (total >= K) && (total <= LSEL);

    if (fits) {               // compact 32 slices into lcKey/lcIdx: 8 thr/slice
        const int sl = tid >> 3;
        const int j0 = tid & 7;
        const unsigned long long* src = cand + (size_t)(p * SPLIT + sl) * SLICE_CAP;
        const int c = scnt[sl];
        const int o = soff[sl];
        for (int j = j0; j < c; j += 8) {
            unsigned long long e = src[j];
            lcKey[o + j] = (unsigned)(e >> 32);
            lcIdx[o + j] = (unsigned)(e & 0xffffffffu);
        }
    }
    __syncthreads();

    const float4* p4 = (const float4*)pairSrc(p, rv, ri, rf);

    if (tid == 0) { s_p2 = 0; s_b2 = 0; s_cg2 = 0; }
    __syncthreads();

    while (s_b2 < 32) {       // 4 passes x 8 bits
        hist[tid] = 0;        // NTS == 256
        __syncthreads();
        {
            const int b2 = s_b2; const unsigned p2 = s_p2;
            const int sh2 = 24 - b2;
            if (fits) {
                for (int i = tid; i < total; i += NTS) {
                    unsigned kk = lcKey[i];
                    bool match = (b2 == 0) || ((kk >> (32 - b2)) == p2);
                    if (match) atomicAdd(&hist[(kk >> sh2) & 255u], 1u);
                }
            } else {          // fallback: full-image scan (degenerate only)
                for (int i = tid; i < N_ELEM / 4; i += NTS) {
                    float4 v = p4[i];
                    unsigned kk;
                    kk = keyOf(v.x); if ((b2 == 0) || ((kk >> (32 - b2)) == p2)) atomicAdd(&hist[(kk >> sh2) & 255u], 1u);
                    kk = keyOf(v.y); if ((b2 == 0) || ((kk >> (32 - b2)) == p2)) atomicAdd(&hist[(kk >> sh2) & 255u], 1u);
                    kk = keyOf(v.z); if ((b2 == 0) || ((kk >> (32 - b2)) == p2)) atomicAdd(&hist[(kk >> sh2) & 255u], 1u);
                    kk = keyOf(v.w); if ((b2 == 0) || ((kk >> (32 - b2)) == p2)) atomicAdd(&hist[(kk >> sh2) & 255u], 1u);
                }
            }
        }
        __syncthreads();
        const unsigned r = (unsigned)(K - s_cg2);
        if (tid < 64) {       // single-wave suffix-scan pick (4 bins/lane)
            const int l = tid;
            unsigned h0 = hist[4*l+0], h1 = hist[4*l+1], h2 = hist[4*l+2], h3 = hist[4*l+3];
            unsigned suf = h0 + h1 + h2 + h3;
            #pragma unroll
            for (int off = 1; off < 64; off <<= 1) {
                unsigned u = __shfl_down(suf, off, 64);
                if (l + off < 64) suf += u;
            }
            unsigned s0 = suf, s1 = s0 - h0, s2 = s1 - h1, s3 = s2 - h2, s4 = s3 - h3;
            int d = -1; unsigned below = 0;
            if      (s3 >= r && s4 < r) { d = 4*l+3; below = s4; }
            else if (s2 >= r && s3 < r) { d = 4*l+2; below = s3; }
            else if (s1 >= r && s2 < r) { d = 4*l+1; below = s2; }
            else if (s0 >= r && s1 < r) { d = 4*l+0; below = s1; }
            if (d >= 0) { s_pickd = d; s_pickb = below; }   // exactly one lane
        }
        __syncthreads();
        if (tid == 0) {
            s_p2 = (s_p2 << 8) | (unsigned)s_pickd;
            s_cg2 += (int)s_pickb;
            s_b2 += 8;
        }
        __syncthreads();
    }

    if (tid == 0) { s_on = 0; s_tn = 0; }
    __syncthreads();
    {
        const unsigned Kth = s_p2;
        if (fits) {
            for (int i = tid; i < total; i += NTS) {
                unsigned kk = lcKey[i];
                int idx = (int)lcIdx[i];
                if (kk > Kth) { int pos = atomicAdd(&s_on, 1); obuf[pos] = idx; }
                else if (kk == Kth) { int pos = atomicAdd(&s_tn, 1); if (pos < TIE_CAP) ties[pos] = idx; }
            }
        } else {
            for (int i = tid; i < N_ELEM / 4; i += NTS) {
                float4 v = p4[i];
                float vals[4] = {v.x, v.y, v.z, v.w};
                for (int c = 0; c < 4; ++c) {
                    unsigned kk = keyOf(vals[c]);
                    if (kk > Kth) { int pos = atomicAdd(&s_on, 1); obuf[pos] = 4 * i + c; }
                    else if (kk == Kth) { int pos = atomicAdd(&s_tn, 1); if (pos < TIE_CAP) ties[pos] = 4 * i + c; }
                }
            }
        }
    }
    __syncthreads();
    if (tid == 0) {
        int need = K - s_cg2;                       // tie slots (>=1)
        int tn = s_tn; if (tn > TIE_CAP) tn = TIE_CAP;
        int rr = need; if (rr > tn) rr = tn;
        for (int a = 0; a < rr; ++a) {              // rr smallest tie indices
            int mb = a;
            for (int j = a + 1; j < tn; ++j) if (ties[j] < ties[mb]) mb = j;
            int tmp = ties[a]; ties[a] = ties[mb]; ties[mb] = tmp;
            obuf[s_on + a] = ties[a];
        }
        for (int a = rr; a < need; ++a) obuf[s_on + a] = (tn > 0) ? ties[0] : 0;
    }

    __threadfence();
    __syncthreads();
    if (tid == 0) s_last2 = (atomicAdd(&batchCnt[bb], 1) == 2) ? 1 : 0;
    __syncthreads();
    if (!s_last2) return;

    // ================= Phase 3: bitmap coverage for batch bb =================
    __threadfence();          // acquire the other two pairs' obuf writes
    {
        unsigned* rfbm  = (unsigned*)smem;             // 32 KB
        unsigned* srcbm = (unsigned*)(smem + 32768);   // 16 KB (one y-half)
        const int* rvI = idx_out + (size_t)(bb * 3 + 0) * 360;
        const int* riI = idx_out + (size_t)(bb * 3 + 1) * 360;
        const int* rfI = idx_out + (size_t)(bb * 3 + 2) * 360;

        for (int i = tid; i < 8192; i += NTS) rfbm[i] = 0;
        if (tid == 0) { s_u = 0; s_c = 0; }
        __syncthreads();
        for (int i = tid; i < 360; i += NTS) {
            int v = rfI[i];
            atomicOr(&rfbm[v >> 5], 1u << (v & 31));
        }
        __syncthreads();

        int myu = 0, myc = 0;
        for (int h = 0; h < 2; ++h) {
            for (int i = tid; i < 4096; i += NTS) srcbm[i] = 0;
            __syncthreads();
            for (int i = tid; i < 360; i += NTS) {
                int v = (i < 180) ? rvI[i] : riI[i - 180];
                int y = v >> 9, x = v & 511;
                if ((y >> 8) == h) {
                    unsigned bit = 1u << (v & 31);
                    unsigned old = atomicOr(&srcbm[(v >> 5) & 4095], bit);
                    if (!(old & bit)) {
                        myu++;
                        int lo = x - 3; if (lo < 0) lo = 0;
                        int hi = x + 3; if (hi > 511) hi = 511;
                        int k0 = lo >> 5, k1 = hi >> 5;
                        unsigned m0, m1;
                        if (k0 == k1) { m0 = ((1u << (hi - lo + 1)) - 1u) << (lo & 31); m1 = 0u; }
                        else          { m0 = 0xffffffffu << (lo & 31); m1 = (1u << ((hi & 31) + 1)) - 1u; }
                        unsigned cov = 0;
                        #pragma unroll
                        for (int dy = -3; dy <= 3; ++dy) {
                            int yy = y + dy;
                            if (yy >= 0 && yy < 512) {
                                const unsigned* row = &rfbm[yy << 4];
                                cov |= (row[k0] & m0);
                                if (k1 != k0) cov |= (row[k1] & m1);
                            }
                        }
                        myc += (cov != 0u) ? 1 : 0;
                    }
                }
            }
            __syncthreads();
        }
        if (myu) atomicAdd(&s_u, myu);
        if (myc) atomicAdd(&s_c, myc);
        __syncthreads();
        if (tid == 0) {
            float denom = (float)(s_u > 0 ? s_u : 1);
            ((volatile float*)lossArr)[bb] = 1.0f - (float)s_c / denom;
        }
    }
    __threadfence();
    __syncthreads();
    if (tid == 0) s_last3 = (atomicAdd(gcnt, 1) == B - 1) ? 1 : 0;
    __syncthreads();
    if (!s_last3) return;

    // ================= Phase 4: final mean over batches =================
    __threadfence();          // acquire all lossArr stores
    if (tid < 64) {
        float v = 0.0f;
        for (int j = tid; j < B; j += 64) v += ((volatile float*)lossArr)[j];
        #pragma unroll
        for (int off = 32; off; off >>= 1) v += __shfl_down(v, off, 64);
        if (tid == 0) *out = v / (float)B;
    }
}

extern "C" void kernel_launch(void* const* d_in, const int* in_sizes, int n_in,
                              void* d_out, int out_size, void* d_ws, size_t ws_size,
                              hipStream_t stream) {
    const float* rv = (const float*)d_in[0];
    const float* ri = (const float*)d_in[1];
    const float* rf = (const float*)d_in[2];
    float* out = (float*)d_out;

    const int B = in_sizes[0] / N_ELEM;
    const int P = 3 * B;

    // ws layout: cntS (P*SPLIT) | pairCnt (P) | batchCnt (B) | gcnt (1) |
    //            lossArr (B f32) | idx_buf (P*360) | cand (P*SPLIT*SLICE_CAP u64)
    char* ws = (char*)d_ws;
    int* cntS     = (int*)ws;
    int* pairCnt  = cntS + (size_t)P * SPLIT;
    int* batchCnt = pairCnt + P;
    int* gcnt     = batchCnt + B;
    float* lossArr = (float*)(gcnt + 1);
    int* idx_buf  = (int*)(lossArr + B);
    size_t fixed = (size_t)((char*)(idx_buf + (size_t)P * 360) - ws);
    fixed = (fixed + 7) & ~(size_t)7;
    unsigned long long* cand = (unsigned long long*)(ws + fixed);
    // total ~= 6.5 MB for B=32

    init_kernel<<<1, 256, 0, stream>>>(pairCnt, P, batchCnt, B, gcnt);
    fused_kernel<<<P * SPLIT, NTS, 0, stream>>>(rv, ri, rf, cntS, cand, idx_buf,
                                                pairCnt, batchCnt, gcnt, lossArr, out, B);
}

// Round 9
// 147.502 us; speedup vs baseline: 3.5868x; 3.5868x over previous
//
#include <hip/hip_runtime.h>

#define N_ELEM 262144   // 1*512*512 per batch image
#define SPLIT 32        // blocks per (batch,tensor) pair in collect
#define NTS 256         // block size
#define SLICE_CAP 256   // per-slice candidate cap (expected ~51, 28 sigma margin)
#define LSEL 2048       // select: LDS candidate cache entries (expected ~1630)
#define TIE_CAP 512
#define THRESH 2.5f     // fixed pre-filter; select falls back if counts invalid

// Order-preserving float->uint key: larger float => larger key.
__device__ __forceinline__ unsigned keyOf(float f) {
    unsigned u = __float_as_uint(f);
    return (u & 0x80000000u) ? ~u : (u | 0x80000000u);
}

__device__ __forceinline__ const float* pairSrc(int p, const float* rv, const float* ri, const float* rf) {
    int t = p % 3, b = p / 3;
    return (t == 0 ? rv : (t == 1 ? ri : rf)) + (size_t)b * N_ELEM;
}

// ---- Kernel 1: threshold-filter straight into PER-SLICE global regions.
//      Position from an LDS counter; hits are rare (~51/8192) so the
//      scattered 8B stores are negligible. No fences — the kernel boundary
//      provides cross-XCD visibility ONCE (per-block fences were the R8
//      disaster: every agent-scope release flushes L2). ----
__global__ __launch_bounds__(NTS) void collect_kernel(const float* __restrict__ rv,
                                                      const float* __restrict__ ri,
                                                      const float* __restrict__ rf,
                                                      int* __restrict__ cntS,
                                                      unsigned long long* __restrict__ cand,
                                                      float* __restrict__ out,
                                                      int* __restrict__ done, int B) {
    const int p = blockIdx.x / SPLIT;
    const int s = blockIdx.x % SPLIT;
    const float4* p4 = (const float4*)pairSrc(p, rv, ri, rf) + (size_t)s * (N_ELEM / 4 / SPLIT);

    __shared__ int s_m;
    const int tid = threadIdx.x;

    if (blockIdx.x == 0) {            // once per launch: zero out + done[]
        if (tid < B) done[tid] = 0;
        if (tid == B) *out = 0.0f;
    }
    if (tid == 0) s_m = 0;
    __syncthreads();

    unsigned long long* my = cand + (size_t)(p * SPLIT + s) * SLICE_CAP;
    const int base_idx = s * (N_ELEM / SPLIT);
    for (int i = tid; i < N_ELEM / 4 / SPLIT; i += NTS) {   // 8 iterations
        float4 v = p4[i];
        int pos;
        if (v.x > THRESH) { pos = atomicAdd(&s_m, 1); if (pos < SLICE_CAP) my[pos] = ((unsigned long long)keyOf(v.x) << 32) | (unsigned)(base_idx + 4 * i + 0); }
        if (v.y > THRESH) { pos = atomicAdd(&s_m, 1); if (pos < SLICE_CAP) my[pos] = ((unsigned long long)keyOf(v.y) << 32) | (unsigned)(base_idx + 4 * i + 1); }
        if (v.z > THRESH) { pos = atomicAdd(&s_m, 1); if (pos < SLICE_CAP) my[pos] = ((unsigned long long)keyOf(v.z) << 32) | (unsigned)(base_idx + 4 * i + 2); }
        if (v.w > THRESH) { pos = atomicAdd(&s_m, 1); if (pos < SLICE_CAP) my[pos] = ((unsigned long long)keyOf(v.w) << 32) | (unsigned)(base_idx + 4 * i + 3); }
    }
    __syncthreads();
    if (tid == 0) {
        int m = s_m;
        cntS[p * SPLIT + s] = (m > SLICE_CAP) ? -1 : m;   // -1 => overflow => fallback
    }
}

// ---- Kernel 2: exact rank-K radix select per pair (LDS-cached candidates),
//      fused with bitmap coverage via per-batch done-counter. ----
// Shared-memory union (48 KB), temporally disjoint uses:
//   select phase:  lcKey[2048] (8K) | lcIdx[2048] (8K)         [first 16 KB]
//   coverage:      rfbm[8192] (32K) | srcbm[4096] (16K)        [all 48 KB]
__global__ __launch_bounds__(NTS) void select_cov_kernel(const float* __restrict__ rv,
                                                         const float* __restrict__ ri,
                                                         const float* __restrict__ rf,
                                                         const int* __restrict__ cntS,
                                                         const unsigned long long* __restrict__ cand,
                                                         int* __restrict__ idx_out,
                                                         int* __restrict__ done,
                                                         float* __restrict__ out,
                                                         float inv_b) {
    const int p = blockIdx.x;
    const int t = p % 3;
    const int bb = p / 3;
    const int K = (t == 2) ? 360 : 180;
    int* obuf = idx_out + (size_t)p * 360;
    const int tid = threadIdx.x;

    __shared__ __align__(16) unsigned char smem[49152];   // 48 KB union
    unsigned* lcKey = (unsigned*)smem;            // 8 KB
    unsigned* lcIdx = (unsigned*)(smem + 8192);   // 8 KB
    __shared__ unsigned hist[256];
    __shared__ int ties[TIE_CAP];
    __shared__ int soff[SPLIT]; __shared__ int scnt[SPLIT];
    __shared__ int s_total, s_bad, s_minB, s_maxB;
    __shared__ unsigned s_p2; __shared__ int s_b2; __shared__ int s_cg2;
    __shared__ int s_on, s_tn, s_pickd; __shared__ unsigned s_pickb;
    __shared__ int s_prev, s_u, s_c;

    // slice counts -> offsets (wave 0, shfl scan; no barriers inside)
    if (tid < 64) {
        int c = (tid < SPLIT) ? cntS[p * SPLIT + tid] : 0;
        int bad = (c < 0) ? 1 : 0;
        int cc = bad ? 0 : c;
        int v = cc;
        #pragma unroll
        for (int off = 1; off < 64; off <<= 1) {
            int u = __shfl_up(v, off, 64);
            if (tid >= off) v += u;
        }
        if (tid < SPLIT) { soff[tid] = v - cc; scnt[tid] = cc; }
        if (tid == 63) s_total = v;
        unsigned long long bm = __ballot(bad != 0);
        if (tid == 0) { s_bad = (bm != 0ull) ? 1 : 0; s_minB = 256; s_maxB = -1; }
    }
    __syncthreads();
    const int total = s_total;
    const bool fits = (!s_bad) && (total >= K) && (total <= LSEL);

    if (fits) {   // compact the 32 slices into lcKey/lcIdx: 8 threads per slice
        const int sl = tid >> 3;
        const int j0 = tid & 7;
        const unsigned long long* src = cand + (size_t)(p * SPLIT + sl) * SLICE_CAP;
        const int c = scnt[sl];
        const int o = soff[sl];
        int lmin = 256, lmax = -1;
        for (int j = j0; j < c; j += 8) {
            unsigned long long e = src[j];
            unsigned kk = (unsigned)(e >> 32);
            lcKey[o + j] = kk;
            lcIdx[o + j] = (unsigned)(e & 0xffffffffu);
            int tb = (int)(kk >> 24);
            if (tb < lmin) lmin = tb;
            if (tb > lmax) lmax = tb;
        }
        if (lmax >= 0) { atomicMin(&s_minB, lmin); atomicMax(&s_maxB, lmax); }
    }
    __syncthreads();

    const float4* p4 = (const float4*)pairSrc(p, rv, ri, rf);

    if (tid == 0) {
        s_p2 = 0; s_b2 = 0; s_cg2 = 0;
        // all candidate keys share the top byte -> pass 1 is a foregone
        // conclusion (pick that byte, nothing above it): skip it exactly.
        if (fits && s_maxB >= 0 && s_minB == s_maxB) { s_p2 = (unsigned)s_minB; s_b2 = 8; }
    }
    __syncthreads();

    // remaining radix passes (8 bits each)
    while (s_b2 < 32) {
        hist[tid] = 0;                        // NTS == 256
        __syncthreads();
        {
            const int b2 = s_b2; const unsigned p2 = s_p2;
            const int sh2 = 24 - b2;
            if (fits) {
                for (int i = tid; i < total; i += NTS) {
                    unsigned kk = lcKey[i];
                    bool match = (b2 == 0) || ((kk >> (32 - b2)) == p2);
                    if (match) atomicAdd(&hist[(kk >> sh2) & 255u], 1u);
                }
            } else {   // fallback: full-image scan (degenerate inputs only)
                for (int i = tid; i < N_ELEM / 4; i += NTS) {
                    float4 v = p4[i];
                    unsigned kk;
                    kk = keyOf(v.x); if ((b2 == 0) || ((kk >> (32 - b2)) == p2)) atomicAdd(&hist[(kk >> sh2) & 255u], 1u);
                    kk = keyOf(v.y); if ((b2 == 0) || ((kk >> (32 - b2)) == p2)) atomicAdd(&hist[(kk >> sh2) & 255u], 1u);
                    kk = keyOf(v.z); if ((b2 == 0) || ((kk >> (32 - b2)) == p2)) atomicAdd(&hist[(kk >> sh2) & 255u], 1u);
                    kk = keyOf(v.w); if ((b2 == 0) || ((kk >> (32 - b2)) == p2)) atomicAdd(&hist[(kk >> sh2) & 255u], 1u);
                }
            }
        }
        __syncthreads();
        const unsigned r = (unsigned)(K - s_cg2);
        if (tid < 64) {   // single-wave suffix-scan pick (4 bins/lane)
            const int l = tid;
            unsigned h0 = hist[4*l+0], h1 = hist[4*l+1], h2 = hist[4*l+2], h3 = hist[4*l+3];
            unsigned suf = h0 + h1 + h2 + h3;
            #pragma unroll
            for (int off = 1; off < 64; off <<= 1) {
                unsigned u = __shfl_down(suf, off, 64);
                if (l + off < 64) suf += u;
            }
            unsigned s0 = suf, s1 = s0 - h0, s2 = s1 - h1, s3 = s2 - h2, s4 = s3 - h3;
            int d = -1; unsigned below = 0;
            if      (s3 >= r && s4 < r) { d = 4*l+3; below = s4; }
            else if (s2 >= r && s3 < r) { d = 4*l+2; below = s3; }
            else if (s1 >= r && s2 < r) { d = 4*l+1; below = s2; }
            else if (s0 >= r && s1 < r) { d = 4*l+0; below = s1; }
            if (d >= 0) { s_pickd = d; s_pickb = below; }   // exactly one lane
        }
        __syncthreads();
        if (tid == 0) {
            s_p2 = (s_p2 << 8) | (unsigned)s_pickd;
            s_cg2 += (int)s_pickb;
            s_b2 += 8;
        }
        __syncthreads();
    }

    if (tid == 0) { s_on = 0; s_tn = 0; }
    __syncthreads();

    // emit: key > Kth directly; key == Kth to tie buffer
    {
        const unsigned Kth = s_p2;
        if (fits) {
            for (int i = tid; i < total; i += NTS) {
                unsigned kk = lcKey[i];
                int idx = (int)lcIdx[i];
                if (kk > Kth) { int pos = atomicAdd(&s_on, 1); obuf[pos] = idx; }
                else if (kk == Kth) { int pos = atomicAdd(&s_tn, 1); if (pos < TIE_CAP) ties[pos] = idx; }
            }
        } else {
            for (int i = tid; i < N_ELEM / 4; i += NTS) {
                float4 v = p4[i];
                float vals[4] = {v.x, v.y, v.z, v.w};
                for (int c = 0; c < 4; ++c) {
                    unsigned kk = keyOf(vals[c]);
                    if (kk > Kth) { int pos = atomicAdd(&s_on, 1); obuf[pos] = 4 * i + c; }
                    else if (kk == Kth) { int pos = atomicAdd(&s_tn, 1); if (pos < TIE_CAP) ties[pos] = 4 * i + c; }
                }
            }
        }
    }
    __syncthreads();
    if (tid == 0) {
        int need = K - s_cg2;                       // tie slots to fill (>=1)
        int tn = s_tn; if (tn > TIE_CAP) tn = TIE_CAP;
        int rr = need; if (rr > tn) rr = tn;        // safety clamp (degenerate only)
        for (int a = 0; a < rr; ++a) {              // selection sort: rr smallest indices
            int mb = a;
            for (int j = a + 1; j < tn; ++j) if (ties[j] < ties[mb]) mb = j;
            int tmp = ties[a]; ties[a] = ties[mb]; ties[mb] = tmp;
            obuf[s_on + a] = ties[a];
        }
        for (int a = rr; a < need; ++a) obuf[s_on + a] = (tn > 0) ? ties[0] : 0;
    }

    // ---- fused coverage (bitmap version): last pair-block of batch bb ----
    __threadfence();                   // release our obuf writes (96 blocks only)
    __syncthreads();                   // also: last read of lcKey/lcIdx before aliasing
    if (tid == 0) s_prev = atomicAdd(&done[bb], 1);
    __syncthreads();
    if (s_prev == 2) {
        __threadfence();               // acquire the other two pairs' writes
        unsigned* rfbm  = (unsigned*)smem;             // 32 KB: 512 rows x 16 words
        unsigned* srcbm = (unsigned*)(smem + 32768);   // 16 KB: one y-half
        const int* rvI = idx_out + (size_t)(bb * 3 + 0) * 360;
        const int* riI = idx_out + (size_t)(bb * 3 + 1) * 360;
        const int* rfI = idx_out + (size_t)(bb * 3 + 2) * 360;

        for (int i = tid; i < 8192; i += NTS) rfbm[i] = 0;
        if (tid == 0) { s_u = 0; s_c = 0; }
        __syncthreads();
        for (int i = tid; i < 360; i += NTS) {
            int v = rfI[i];
            atomicOr(&rfbm[v >> 5], 1u << (v & 31));
        }
        __syncthreads();

        int myu = 0, myc = 0;
        for (int h = 0; h < 2; ++h) {              // two y-halves share the 16 KB srcbm
            for (int i = tid; i < 4096; i += NTS) srcbm[i] = 0;
            __syncthreads();
            for (int i = tid; i < 360; i += NTS) {
                int v = (i < 180) ? rvI[i] : riI[i - 180];
                int y = v >> 9, x = v & 511;
                if ((y >> 8) == h) {
                    unsigned bit = 1u << (v & 31);
                    unsigned old = atomicOr(&srcbm[(v >> 5) & 4095], bit);
                    if (!(old & bit)) {            // unique in the union set
                        myu++;
                        int lo = x - 3; if (lo < 0) lo = 0;
                        int hi = x + 3; if (hi > 511) hi = 511;
                        int k0 = lo >> 5, k1 = hi >> 5;
                        unsigned m0, m1;
                        if (k0 == k1) { m0 = ((1u << (hi - lo + 1)) - 1u) << (lo & 31); m1 = 0u; }
                        else          { m0 = 0xffffffffu << (lo & 31); m1 = (1u << ((hi & 31) + 1)) - 1u; }
                        unsigned cov = 0;
                        #pragma unroll
                        for (int dy = -3; dy <= 3; ++dy) {
                            int yy = y + dy;
                            if (yy >= 0 && yy < 512) {
                                const unsigned* row = &rfbm[yy << 4];
                                cov |= (row[k0] & m0);
                                if (k1 != k0) cov |= (row[k1] & m1);
                            }
                        }
                        myc += (cov != 0u) ? 1 : 0;
                    }
                }
            }
            __syncthreads();
        }
        if (myu) atomicAdd(&s_u, myu);
        if (myc) atomicAdd(&s_c, myc);
        __syncthreads();
        if (tid == 0) {
            float denom = (float)(s_u > 0 ? s_u : 1);
            float loss = 1.0f - (float)s_c / denom;
            atomicAdd(out, loss * inv_b);
        }
    }
}

extern "C" void kernel_launch(void* const* d_in, const int* in_sizes, int n_in,
                              void* d_out, int out_size, void* d_ws, size_t ws_size,
                              hipStream_t stream) {
    const float* rv = (const float*)d_in[0];
    const float* ri = (const float*)d_in[1];
    const float* rf = (const float*)d_in[2];
    float* out = (float*)d_out;

    const int B = in_sizes[0] / N_ELEM;
    const int P = 3 * B;

    // workspace: cntS (P*SPLIT ints) | done (B ints) | idx_buf (P*360 ints) | cand
    char* ws = (char*)d_ws;
    int* cntS = (int*)ws;
    int* done = (int*)(ws + (size_t)P * SPLIT * 4);
    int* idx_buf = (int*)(ws + (size_t)P * SPLIT * 4 + (size_t)B * 4);
    size_t fixed = (size_t)P * SPLIT * 4 + (size_t)B * 4 + (size_t)P * 360 * 4;
    fixed = (fixed + 7) & ~(size_t)7;
    unsigned long long* cand = (unsigned long long*)(ws + fixed);
    // needs fixed + P*SPLIT*SLICE_CAP*8 bytes ~= 6.5 MB for B=32

    collect_kernel<<<P * SPLIT, NTS, 0, stream>>>(rv, ri, rf, cntS, cand, out, done, B);
    select_cov_kernel<<<P, NTS, 0, stream>>>(rv, ri, rf, cntS, cand, idx_buf, done, out, 1.0f / (float)B);
}